// Round 1
// baseline (906.963 us; speedup 1.0000x reference)
//
#include <hip/hip_runtime.h>

typedef __attribute__((ext_vector_type(8))) short short8;
typedef __attribute__((ext_vector_type(4))) float floatx4;
typedef __attribute__((ext_vector_type(2))) float floatx2;
typedef __attribute__((ext_vector_type(4))) unsigned short ushort4v;
typedef __attribute__((ext_vector_type(2))) unsigned int uint2v;

#define DEVI static __device__ __forceinline__

DEVI unsigned short f2bf(float f) {
  unsigned int u = __float_as_uint(f);
  u = (u + 0x7fffu + ((u >> 16) & 1u)) >> 16;   // RNE
  return (unsigned short)u;
}
DEVI float bf2f(unsigned short h) { return __uint_as_float(((unsigned int)h) << 16); }

// residual LDS index: [c][t] bf16, t XOR-swizzled by c to break 8-way conflicts
DEVI int ridx(int c, int t) { return c * 64 + (t ^ ((c & 7) << 3)); }

// ---------------- weight fp32 -> bf16 prelude ----------------
__global__ void wconv(const float* __restrict__ wqkv, const float* __restrict__ wout,
                      unsigned short* __restrict__ wbf) {
  int i = blockIdx.x * 256 + threadIdx.x;
#pragma unroll
  for (int k = 0; k < 4; ++k) {
    int idx = i + k * 65536;
    float v = (idx < 196608) ? wqkv[idx] : wout[idx - 196608];
    wbf[idx] = f2bf(v);
  }
}

// ---------------- fused LN + window-MHA + proj + residual ----------------
__global__ __launch_bounds__(256, 2) void fused_kernel(
    const float* __restrict__ x, const float* __restrict__ gamma,
    const float* __restrict__ beta, const unsigned short* __restrict__ wbf,
    float* __restrict__ out) {
  // sxn: LN partials -> xn (frag-order bf16) -> o (frag-order bf16)   32KB
  // sres: residual bf16 [c][t] swizzled                               32KB
  __shared__ __align__(16) unsigned short sxn[64 * 256];
  __shared__ __align__(16) unsigned short sres[256 * 64];

  const int tid = threadIdx.x;
  const int lane = tid & 63;
  const int wv = tid >> 6;        // wave = head
  const int g = lane >> 4;        // MFMA lane group
  const int l15 = lane & 15;

  // XCD-chunked swizzle: 4096 blocks, 8 XCDs, 512 contiguous ids per XCD
  int id = ((blockIdx.x & 7) << 9) + (blockIdx.x >> 3);
  const int b = id >> 10;
  const int wy = (id >> 5) & 31;
  const int wx = id & 31;
  const size_t xbase = ((size_t)b << 24) + (size_t)(wy * 8) * 256 + (size_t)(wx * 8);
  // x[(b*256+c)*65536 + (h0+i)*256 + (w0+j)] = x[xbase + c*65536 + i*256 + j]

  // ---- Phase A: load x window -> sres (bf16) ----
#pragma unroll
  for (int it = 0; it < 16; ++it) {
    int s = tid + it * 256;                  // [0,4096)
    int c = s >> 4, i = (s >> 1) & 7, jh = s & 1;
    floatx4 v = *(const floatx4*)(x + xbase + (size_t)c * 65536 + i * 256 + jh * 4);
    ushort4v u;
    u.x = f2bf(v.x); u.y = f2bf(v.y); u.z = f2bf(v.z); u.w = f2bf(v.w);
    *(ushort4v*)&sres[ridx(c, i * 8 + jh * 4)] = u;
  }
  __syncthreads();

  // ---- Phase B1: LN partial sums. lane = token, wave = channel quarter ----
  float s1 = 0.f, s2 = 0.f;
#pragma unroll 8
  for (int cc = 0; cc < 64; ++cc) {
    float xv = bf2f(sres[ridx(wv * 64 + cc, lane)]);
    s1 += xv; s2 += xv * xv;
  }
  {
    floatx2 p; p.x = s1; p.y = s2;
    ((floatx2*)sxn)[wv * 64 + lane] = p;
  }
  __syncthreads();

  // ---- Phase B2a: combine stats (every wave, redundantly, for token=lane) ----
  float S1 = 0.f, S2 = 0.f;
#pragma unroll
  for (int p = 0; p < 4; ++p) {
    floatx2 pp = ((const floatx2*)sxn)[p * 64 + lane];
    S1 += pp.x; S2 += pp.y;
  }
  const float mu = S1 * (1.f / 256.f);
  const float rstd = rsqrtf(S2 * (1.f / 256.f) - mu * mu + 1e-5f);
  __syncthreads();   // partials consumed before xn overwrites them

  // ---- Phase B2b: write xn bf16 in fragment order + chunk swizzle ----
  {
    const int t = lane;
#pragma unroll
    for (int kk = 0; kk < 2; ++kk) {
      int kc = wv * 2 + kk;
#pragma unroll
      for (int gc = 0; gc < 4; ++gc) {
        short8 s8;
#pragma unroll
        for (int hf = 0; hf < 2; ++hf)
#pragma unroll
          for (int e = 0; e < 4; ++e) {
            int c = kc * 32 + hf * 16 + gc * 4 + e;          // lane-uniform
            float xv = bf2f(sres[ridx(c, t)]);
            float val = (xv - mu) * rstd * gamma[c] + beta[c];
            s8[hf * 4 + e] = (short)f2bf(val);
          }
        *(short8*)&sxn[t * 256 + ((((kc << 2) + gc) ^ (t & 7)) << 3)] = s8;
      }
    }
  }
  __syncthreads();

  // fragment loaders ------------------------------------------------------
  auto ldsfrag = [&](int row, int kc) -> short8 {   // A or B frag from sxn-style buffer
    return *(const short8*)&sxn[row * 256 + ((((kc << 2) + g) ^ (row & 7)) << 3)];
  };
  auto wfrag = [&](const unsigned short* wrow, int kc) -> short8 {  // weight row frag
    union { short8 s8; uint2v u2[2]; } u;
    u.u2[0] = *(const uint2v*)(wrow + kc * 32 + (g << 2));
    u.u2[1] = *(const uint2v*)(wrow + kc * 32 + 16 + (g << 2));
    return u.s8;
  };

  // ---- Phase C: per-head qT, kT (transposed GEMMs) and v (normal GEMM) ----
  short8 qkf[2][4][2];   // [q/k][tile][kslice] -> S-GEMM B/A frags
#pragma unroll
  for (int qk = 0; qk < 2; ++qk) {
    floatx4 acc[4][4] = {};            // [mt = d-tile][nt = t-tile]
    const int wrowbase = qk * 256 + wv * 64;
#pragma unroll
    for (int kc = 0; kc < 8; ++kc) {
      short8 Bv[4], Av[4];
#pragma unroll
      for (int nt = 0; nt < 4; ++nt) Bv[nt] = ldsfrag(nt * 16 + l15, kc);  // xn as B
#pragma unroll
      for (int mt = 0; mt < 4; ++mt)
        Av[mt] = wfrag(wbf + (size_t)(wrowbase + mt * 16 + l15) * 256, kc); // W rows as A
#pragma unroll
      for (int mt = 0; mt < 4; ++mt)
#pragma unroll
        for (int nt = 0; nt < 4; ++nt)
          acc[mt][nt] = __builtin_amdgcn_mfma_f32_16x16x32_bf16(Av[mt], Bv[nt], acc[mt][nt], 0, 0, 0);
    }
#pragma unroll
    for (int nt = 0; nt < 4; ++nt)
#pragma unroll
      for (int ks = 0; ks < 2; ++ks) {
        short8 f;
#pragma unroll
        for (int e = 0; e < 4; ++e) {
          f[e]     = (short)f2bf(acc[2 * ks][nt][e]);
          f[4 + e] = (short)f2bf(acc[2 * ks + 1][nt][e]);
        }
        qkf[qk][nt][ks] = f;
      }
  }

  short8 vf[4][2];   // [d-tile][kslice] -> PV B frags
  {
    floatx4 acc[4][4] = {};            // [mt = t-tile][nt = d-tile]
#pragma unroll
    for (int kc = 0; kc < 8; ++kc) {
      short8 Av[4], Bv[4];
#pragma unroll
      for (int mt = 0; mt < 4; ++mt) Av[mt] = ldsfrag(mt * 16 + l15, kc);  // xn as A
#pragma unroll
      for (int nt = 0; nt < 4; ++nt)
        Bv[nt] = wfrag(wbf + (size_t)(512 + wv * 64 + nt * 16 + l15) * 256, kc);
#pragma unroll
      for (int mt = 0; mt < 4; ++mt)
#pragma unroll
        for (int nt = 0; nt < 4; ++nt)
          acc[mt][nt] = __builtin_amdgcn_mfma_f32_16x16x32_bf16(Av[mt], Bv[nt], acc[mt][nt], 0, 0, 0);
    }
#pragma unroll
    for (int nt = 0; nt < 4; ++nt)
#pragma unroll
      for (int ks = 0; ks < 2; ++ks) {
        short8 f;
#pragma unroll
        for (int e = 0; e < 4; ++e) {
          f[e]     = (short)f2bf(acc[2 * ks][nt][e]);
          f[4 + e] = (short)f2bf(acc[2 * ks + 1][nt][e]);
        }
        vf[nt][ks] = f;
      }
  }

  // ---- Phase D: S^T = K·Q^T, softmax (column-local), P^T, PV ----
  floatx4 sa[4][4] = {};   // [mts = tk-tile][nts = tq-tile]
#pragma unroll
  for (int ks = 0; ks < 2; ++ks)
#pragma unroll
    for (int mts = 0; mts < 4; ++mts)
#pragma unroll
      for (int nts = 0; nts < 4; ++nts)
        sa[mts][nts] = __builtin_amdgcn_mfma_f32_16x16x32_bf16(qkf[1][mts][ks], qkf[0][nts][ks], sa[mts][nts], 0, 0, 0);

  short8 pf[4][2];
  const float CEXP = 0.125f * 1.44269504088896f;   // scale * log2(e)
#pragma unroll
  for (int nts = 0; nts < 4; ++nts) {
    float m = sa[0][nts][0];
#pragma unroll
    for (int mts = 0; mts < 4; ++mts)
#pragma unroll
      for (int r = 0; r < 4; ++r) m = fmaxf(m, sa[mts][nts][r]);
    m = fmaxf(m, __shfl_xor(m, 16));
    m = fmaxf(m, __shfl_xor(m, 32));
    float sum = 0.f;
#pragma unroll
    for (int mts = 0; mts < 4; ++mts)
#pragma unroll
      for (int r = 0; r < 4; ++r) {
        float p = __builtin_amdgcn_exp2f((sa[mts][nts][r] - m) * CEXP);
        sa[mts][nts][r] = p;
        sum += p;
      }
    sum += __shfl_xor(sum, 16);
    sum += __shfl_xor(sum, 32);
    float inv = __builtin_amdgcn_rcpf(sum);
#pragma unroll
    for (int ks = 0; ks < 2; ++ks) {
      short8 f;
#pragma unroll
      for (int e = 0; e < 4; ++e) {
        f[e]     = (short)f2bf(sa[2 * ks][nts][e] * inv);
        f[4 + e] = (short)f2bf(sa[2 * ks + 1][nts][e] * inv);
      }
      pf[nts][ks] = f;
    }
  }

  floatx4 oa[4][4] = {};   // [ntq = tq-tile][dt = d-tile]
#pragma unroll
  for (int ks = 0; ks < 2; ++ks)
#pragma unroll
    for (int ntq = 0; ntq < 4; ++ntq)
#pragma unroll
      for (int dt = 0; dt < 4; ++dt)
        oa[ntq][dt] = __builtin_amdgcn_mfma_f32_16x16x32_bf16(pf[ntq][ks], vf[dt][ks], oa[ntq][dt], 0, 0, 0);

  __syncthreads();   // all waves done reading xn -> safe to overwrite with o

  // write O -> sxn in fragment order (+swizzle)
#pragma unroll
  for (int ntq = 0; ntq < 4; ++ntq)
#pragma unroll
    for (int dt = 0; dt < 4; ++dt)
#pragma unroll
      for (int r = 0; r < 4; ++r) {
        int tq = ntq * 16 + 4 * g + r;
        int c = wv * 64 + dt * 16 + l15;
        int chunk = ((c >> 5) << 2) + ((c >> 2) & 3);
        sxn[tq * 256 + ((chunk ^ (tq & 7)) << 3) + (((c >> 4) & 1) << 2) + (c & 3)] =
            f2bf(oa[ntq][dt][r]);
      }
  __syncthreads();

  // ---- Phase E: transposed out-GEMM  out^T[co][t] = Wout · o^T  + residual ----
  floatx4 fa[4][4] = {};   // [mt = co-tile][nt = t-tile]
#pragma unroll
  for (int kc = 0; kc < 8; ++kc) {
    short8 Av[4], Bv[4];
#pragma unroll
    for (int nt = 0; nt < 4; ++nt) Bv[nt] = ldsfrag(nt * 16 + l15, kc);   // o as B
#pragma unroll
    for (int mt = 0; mt < 4; ++mt)
      Av[mt] = wfrag(wbf + 196608 + (size_t)(wv * 64 + mt * 16 + l15) * 256, kc);
#pragma unroll
    for (int mt = 0; mt < 4; ++mt)
#pragma unroll
      for (int nt = 0; nt < 4; ++nt)
        fa[mt][nt] = __builtin_amdgcn_mfma_f32_16x16x32_bf16(Av[mt], Bv[nt], fa[mt][nt], 0, 0, 0);
  }

#pragma unroll
  for (int mt = 0; mt < 4; ++mt)
#pragma unroll
    for (int nt = 0; nt < 4; ++nt)
#pragma unroll
      for (int r = 0; r < 4; ++r) {
        int co = wv * 64 + mt * 16 + 4 * g + r;
        int tt = nt * 16 + l15;
        float val = fa[mt][nt][r] + bf2f(sres[ridx(co, tt)]);
        out[((size_t)(b * 256 + co) << 16) + (size_t)(wy * 8 + (tt >> 3)) * 256 +
            (wx * 8 + (tt & 7))] = val;
      }
}

extern "C" void kernel_launch(void* const* d_in, const int* in_sizes, int n_in,
                              void* d_out, int out_size, void* d_ws, size_t ws_size,
                              hipStream_t stream) {
  const float* x     = (const float*)d_in[0];
  const float* gamma = (const float*)d_in[1];
  const float* beta  = (const float*)d_in[2];
  const float* wqkv  = (const float*)d_in[3];
  const float* wout  = (const float*)d_in[4];
  float* out = (float*)d_out;
  unsigned short* wbf = (unsigned short*)d_ws;   // 512 KB: Wqkv bf16 then Wout bf16

  wconv<<<256, 256, 0, stream>>>(wqkv, wout, wbf);
  fused_kernel<<<4096, 256, 0, stream>>>(x, gamma, beta, wbf, out);
}

// Round 2
// 675.710 us; speedup vs baseline: 1.3422x; 1.3422x over previous
//
#include <hip/hip_runtime.h>

typedef __attribute__((ext_vector_type(8))) short short8;
typedef __attribute__((ext_vector_type(4))) float floatx4;
typedef __attribute__((ext_vector_type(2))) float floatx2;
typedef __attribute__((ext_vector_type(4))) unsigned short ushort4v;
typedef __attribute__((ext_vector_type(2))) unsigned int uint2v;

#define DEVI static __device__ __forceinline__

DEVI unsigned short f2bf(float f) {
  unsigned int u = __float_as_uint(f);
  u = (u + 0x7fffu + ((u >> 16) & 1u)) >> 16;   // RNE
  return (unsigned short)u;
}
DEVI float bf2f(unsigned short h) { return __uint_as_float(((unsigned int)h) << 16); }

// residual LDS: [c][t] bf16, t in [0,128), swizzled (keeps 4-alignment)
DEVI int ridx2(int c, int t) { return c * 128 + (t ^ ((c & 7) << 3)); }
// xn/o LDS: row = strip token [0,128), 32 chunks of 8 bf16, chunk-swizzled
DEVI int xnaddr(int row, int chunk) { return row * 256 + (((chunk) ^ (row & 7)) << 3); }

// ---------------- weight fp32 -> bf16 prelude ----------------
__global__ void wconv(const float* __restrict__ wqkv, const float* __restrict__ wout,
                      unsigned short* __restrict__ wbf) {
  int i = blockIdx.x * 256 + threadIdx.x;
#pragma unroll
  for (int k = 0; k < 4; ++k) {
    int idx = i + k * 65536;
    float v = (idx < 196608) ? wqkv[idx] : wout[idx - 196608];
    wbf[idx] = f2bf(v);
  }
}

// ---------------- fused LN + 2-window MHA + proj + residual ----------------
__global__ __launch_bounds__(512, 2) void fused_kernel(
    const float* __restrict__ x, const float* __restrict__ gamma,
    const float* __restrict__ beta, const unsigned short* __restrict__ wbf,
    float* __restrict__ out) {
  __shared__ __align__(16) unsigned short sres[256 * 128];  // 64KB residual bf16
  __shared__ __align__(16) unsigned short sxn[128 * 256];   // 64KB xn / o frags (+LN partials)

  const int tid = threadIdx.x;
  const int lane = tid & 63;
  const int wv = tid >> 6;        // 0..7
  const int g = lane >> 4;
  const int l15 = lane & 15;

  // XCD-chunked swizzle: 2048 blocks, 8 XCDs, 256 contiguous ids per XCD
  const int id = ((blockIdx.x & 7) << 8) + (blockIdx.x >> 3);
  const int b = id >> 9;                 // batch 0..3
  const int wy = (id >> 4) & 31;         // window-row 0..31
  const int wxp = id & 15;               // window-pair 0..15 (16 cols each)
  const size_t xbase = ((size_t)b << 24) + (size_t)(wy * 8) * 256 + (size_t)(wxp * 16);

  // ---- Phase A: load x strip (8 rows x 16 cols x 256 ch) -> sres bf16 ----
#pragma unroll
  for (int it = 0; it < 16; ++it) {
    int s = it * 512 + tid;              // [0,8192)
    int c = s >> 5, i = (s >> 2) & 7, j4 = s & 3;
    floatx4 v = *(const floatx4*)(x + xbase + (size_t)c * 65536 + i * 256 + j4 * 4);
    ushort4v u;
    u.x = f2bf(v.x); u.y = f2bf(v.y); u.z = f2bf(v.z); u.w = f2bf(v.w);
    *(ushort4v*)&sres[ridx2(c, i * 16 + j4 * 4)] = u;
  }
  __syncthreads();

  // ---- Phase B1: LN partial sums. thread = (strip token, channel quarter) ----
  const int t = tid & 127;
  const int q = tid >> 7;
  float s1 = 0.f, s2 = 0.f;
#pragma unroll 8
  for (int cc = 0; cc < 64; ++cc) {
    float xv = bf2f(sres[ridx2(q * 64 + cc, t)]);
    s1 += xv; s2 += xv * xv;
  }
  {
    floatx2 p; p.x = s1; p.y = s2;
    ((floatx2*)sxn)[q * 128 + t] = p;
  }
  __syncthreads();

  // ---- Phase B2a: combine stats ----
  float S1 = 0.f, S2 = 0.f;
#pragma unroll
  for (int p = 0; p < 4; ++p) {
    floatx2 pp = ((const floatx2*)sxn)[p * 128 + t];
    S1 += pp.x; S2 += pp.y;
  }
  const float mu = S1 * (1.f / 256.f);
  const float rstd = rsqrtf(S2 * (1.f / 256.f) - mu * mu + 1e-5f);
  __syncthreads();   // partials consumed before xn overwrites them

  // ---- Phase B2b: write xn bf16 in fragment order ----
#pragma unroll
  for (int kk = 0; kk < 2; ++kk) {
    int kc = q * 2 + kk;
#pragma unroll
    for (int gc = 0; gc < 4; ++gc) {
      short8 s8;
#pragma unroll
      for (int hf = 0; hf < 2; ++hf)
#pragma unroll
        for (int e = 0; e < 4; ++e) {
          int c = kc * 32 + hf * 16 + gc * 4 + e;          // wave-uniform
          float xv = bf2f(sres[ridx2(c, t)]);
          float val = (xv - mu) * rstd * gamma[c] + beta[c];
          s8[hf * 4 + e] = (short)f2bf(val);
        }
      *(short8*)&sxn[xnaddr(t, kc * 4 + gc)] = s8;
    }
  }
  __syncthreads();

  // fragment loaders ------------------------------------------------------
  auto ldsfrag = [&](int row, int kc) -> short8 {
    return *(const short8*)&sxn[xnaddr(row, kc * 4 + g)];
  };
  auto wfrag = [&](const unsigned short* wrow, int kc) -> short8 {
    union { short8 s8; uint2v u2[2]; } u;
    u.u2[0] = *(const uint2v*)(wrow + kc * 32 + (g << 2));
    u.u2[1] = *(const uint2v*)(wrow + kc * 32 + 16 + (g << 2));
    return u.s8;
  };

  // wave roles for attention: head = wv>>1, window = wv&1
  const int head = wv >> 1;
  const int win = wv & 1;
  auto srow = [&](int tl) {  // window-local token -> strip row
    return (((tl) >> 3) << 4) + win * 8 + ((tl) & 7);
  };

  // ---- Phase C: per-(head,win) qT, kT (transposed GEMMs) and v ----
  short8 qkf[2][4][2];
#pragma unroll
  for (int qk = 0; qk < 2; ++qk) {
    floatx4 acc[4][4] = {};            // [mt = d-tile][nt = t-tile]
    const int wrowbase = qk * 256 + head * 64;
#pragma unroll
    for (int kc = 0; kc < 8; ++kc) {
      short8 Bv[4], Av[4];
#pragma unroll
      for (int nt = 0; nt < 4; ++nt) Bv[nt] = ldsfrag(srow(nt * 16 + l15), kc);
#pragma unroll
      for (int mt = 0; mt < 4; ++mt)
        Av[mt] = wfrag(wbf + (size_t)(wrowbase + mt * 16 + l15) * 256, kc);
#pragma unroll
      for (int mt = 0; mt < 4; ++mt)
#pragma unroll
        for (int nt = 0; nt < 4; ++nt)
          acc[mt][nt] = __builtin_amdgcn_mfma_f32_16x16x32_bf16(Av[mt], Bv[nt], acc[mt][nt], 0, 0, 0);
    }
#pragma unroll
    for (int nt = 0; nt < 4; ++nt)
#pragma unroll
      for (int ks = 0; ks < 2; ++ks) {
        short8 f;
#pragma unroll
        for (int e = 0; e < 4; ++e) {
          f[e]     = (short)f2bf(acc[2 * ks][nt][e]);
          f[4 + e] = (short)f2bf(acc[2 * ks + 1][nt][e]);
        }
        qkf[qk][nt][ks] = f;
      }
  }

  short8 vf[4][2];
  {
    floatx4 acc[4][4] = {};            // [mt = t-tile][nt = d-tile]
#pragma unroll
    for (int kc = 0; kc < 8; ++kc) {
      short8 Av[4], Bv[4];
#pragma unroll
      for (int mt = 0; mt < 4; ++mt) Av[mt] = ldsfrag(srow(mt * 16 + l15), kc);
#pragma unroll
      for (int nt = 0; nt < 4; ++nt)
        Bv[nt] = wfrag(wbf + (size_t)(512 + head * 64 + nt * 16 + l15) * 256, kc);
#pragma unroll
      for (int mt = 0; mt < 4; ++mt)
#pragma unroll
        for (int nt = 0; nt < 4; ++nt)
          acc[mt][nt] = __builtin_amdgcn_mfma_f32_16x16x32_bf16(Av[mt], Bv[nt], acc[mt][nt], 0, 0, 0);
    }
#pragma unroll
    for (int nt = 0; nt < 4; ++nt)
#pragma unroll
      for (int ks = 0; ks < 2; ++ks) {
        short8 f;
#pragma unroll
        for (int e = 0; e < 4; ++e) {
          f[e]     = (short)f2bf(acc[2 * ks][nt][e]);
          f[4 + e] = (short)f2bf(acc[2 * ks + 1][nt][e]);
        }
        vf[nt][ks] = f;
      }
  }

  // ---- Phase D: S^T = K.Q^T, softmax (column-local), P^T, PV ----
  floatx4 sa[4][4] = {};
#pragma unroll
  for (int ks = 0; ks < 2; ++ks)
#pragma unroll
    for (int mts = 0; mts < 4; ++mts)
#pragma unroll
      for (int nts = 0; nts < 4; ++nts)
        sa[mts][nts] = __builtin_amdgcn_mfma_f32_16x16x32_bf16(qkf[1][mts][ks], qkf[0][nts][ks], sa[mts][nts], 0, 0, 0);

  short8 pf[4][2];
  const float CEXP = 0.125f * 1.44269504088896f;
#pragma unroll
  for (int nts = 0; nts < 4; ++nts) {
    float m = sa[0][nts][0];
#pragma unroll
    for (int mts = 0; mts < 4; ++mts)
#pragma unroll
      for (int r = 0; r < 4; ++r) m = fmaxf(m, sa[mts][nts][r]);
    m = fmaxf(m, __shfl_xor(m, 16));
    m = fmaxf(m, __shfl_xor(m, 32));
    float sum = 0.f;
#pragma unroll
    for (int mts = 0; mts < 4; ++mts)
#pragma unroll
      for (int r = 0; r < 4; ++r) {
        float p = __builtin_amdgcn_exp2f((sa[mts][nts][r] - m) * CEXP);
        sa[mts][nts][r] = p;
        sum += p;
      }
    sum += __shfl_xor(sum, 16);
    sum += __shfl_xor(sum, 32);
    float inv = __builtin_amdgcn_rcpf(sum);
#pragma unroll
    for (int ks = 0; ks < 2; ++ks) {
      short8 f;
#pragma unroll
      for (int e = 0; e < 4; ++e) {
        f[e]     = (short)f2bf(sa[2 * ks][nts][e] * inv);
        f[4 + e] = (short)f2bf(sa[2 * ks + 1][nts][e] * inv);
      }
      pf[nts][ks] = f;
    }
  }

  floatx4 oa[4][4] = {};   // [ntq = tq-tile][dt = d-tile]
#pragma unroll
  for (int ks = 0; ks < 2; ++ks)
#pragma unroll
    for (int ntq = 0; ntq < 4; ++ntq)
#pragma unroll
      for (int dt = 0; dt < 4; ++dt)
        oa[ntq][dt] = __builtin_amdgcn_mfma_f32_16x16x32_bf16(pf[ntq][ks], vf[dt][ks], oa[ntq][dt], 0, 0, 0);

  __syncthreads();   // all waves done reading xn

  // write O -> sxn in fragment order, strip-token rows
#pragma unroll
  for (int ntq = 0; ntq < 4; ++ntq)
#pragma unroll
    for (int dt = 0; dt < 4; ++dt) {
      int c = head * 64 + dt * 16 + l15;
      int kc = c >> 5, hf = (c >> 4) & 1, gc = (c >> 2) & 3, e = c & 3;
#pragma unroll
      for (int r = 0; r < 4; ++r) {
        int tq = ntq * 16 + 4 * g + r;
        int sr = srow(tq);
        sxn[sr * 256 + (((kc * 4 + gc) ^ (sr & 7)) << 3) + hf * 4 + e] =
            f2bf(oa[ntq][dt][r]);
      }
    }
  __syncthreads();

  // ---- Phase E: strip-wide out-GEMM: wave = 32-channel slice, 128 tokens ----
  floatx4 fa[2][8] = {};   // [mt = co-tile][nt = t-tile]
#pragma unroll
  for (int kc = 0; kc < 8; ++kc) {
    short8 Bv[8], Av[2];
#pragma unroll
    for (int nt = 0; nt < 8; ++nt) Bv[nt] = ldsfrag(nt * 16 + l15, kc);
#pragma unroll
    for (int mt = 0; mt < 2; ++mt)
      Av[mt] = wfrag(wbf + 196608 + (size_t)(wv * 32 + mt * 16 + l15) * 256, kc);
#pragma unroll
    for (int mt = 0; mt < 2; ++mt)
#pragma unroll
      for (int nt = 0; nt < 8; ++nt)
        fa[mt][nt] = __builtin_amdgcn_mfma_f32_16x16x32_bf16(Av[mt], Bv[nt], fa[mt][nt], 0, 0, 0);
  }

#pragma unroll
  for (int mt = 0; mt < 2; ++mt)
#pragma unroll
    for (int nt = 0; nt < 8; ++nt)
#pragma unroll
      for (int r = 0; r < 4; ++r) {
        int co = wv * 32 + mt * 16 + 4 * g + r;
        int tt = nt * 16 + l15;
        float val = fa[mt][nt][r] + bf2f(sres[ridx2(co, tt)]);
        out[((size_t)(b * 256 + co) << 16) + (size_t)(wy * 8 + (tt >> 4)) * 256 +
            (wxp * 16 + (tt & 15))] = val;
      }
}

extern "C" void kernel_launch(void* const* d_in, const int* in_sizes, int n_in,
                              void* d_out, int out_size, void* d_ws, size_t ws_size,
                              hipStream_t stream) {
  const float* x     = (const float*)d_in[0];
  const float* gamma = (const float*)d_in[1];
  const float* beta  = (const float*)d_in[2];
  const float* wqkv  = (const float*)d_in[3];
  const float* wout  = (const float*)d_in[4];
  float* out = (float*)d_out;
  unsigned short* wbf = (unsigned short*)d_ws;   // 512 KB bf16 weights

  wconv<<<256, 256, 0, stream>>>(wqkv, wout, wbf);
  fused_kernel<<<2048, 512, 0, stream>>>(x, gamma, beta, wbf, out);
}